// Round 5
// baseline (298.305 us; speedup 1.0000x reference)
//
#include <hip/hip_runtime.h>
#include <hip/hip_bf16.h>

// LoRALinear with NF4 base: out = x @ W^T + (alpha/rank) * (x@A^T)@B^T
//  Fold: W_eff[o][i] = NF4[codes[o][i]] * scales[o][i/64] + 2 * sum_r B[o][r]*A[r][i]
//  Then one bf16 GEMM: out[M=8192][N=4096] = xb[M][K=4096] . W_eff[N][K]^T
//
// GEMM: 256x256 tile, BK=64 K-tiles, 8-phase interleaved schedule (T3+T4+T5):
// per phase {ds_read frags || 2x global_load_lds stage; barrier; lgkm(0);
// setprio(1); 16 MFMA; setprio(0); barrier}; vmcnt(4) only at phases 4 & 8.
// LDS 128KB = 2 slots x [A_k0|A_k1|B_k0|B_k1] 16KB regions (64B rows,
// R1-verified chunk swizzle c^((r>>1)&3) -> 0 bank conflicts).

#define IN_DIM  4096
#define OUT_DIM 4096
#define RANK    16
#define M_TOK   8192
#define LORA_SCALE 2.0f

typedef __bf16 bf16_t;
typedef bf16_t bf16x8 __attribute__((ext_vector_type(8)));
typedef float  f32x4  __attribute__((ext_vector_type(4)));

__device__ __constant__ float NF4_TAB[16] = {
    -1.0f, -0.6961928009986877f, -0.5250730514526367f, -0.39491748809814453f,
    -0.28444138169288635f, -0.18477343022823334f, -0.09105003625154495f, 0.0f,
    0.07958029955625534f, 0.16093020141124725f, 0.24611230194568634f,
    0.33791524171829224f, 0.44070982933044434f, 0.5626170039176941f,
    0.7229568362236328f, 1.0f};

// ---------------------------------------------------------------- prep W_eff
__global__ __launch_bounds__(256) void prep_w(
    const int* __restrict__ codes, const float* __restrict__ scales,
    const float* __restrict__ la, const float* __restrict__ lb,
    bf16_t* __restrict__ W)
{
    __shared__ float nf4s[16];
    __shared__ float lbs[4][16];
    const int o0 = blockIdx.x * 4;
    const int tid = threadIdx.x;
    if (tid < 64) lbs[tid >> 4][tid & 15] = lb[(o0 + (tid >> 4)) * RANK + (tid & 15)] * LORA_SCALE;
    else if (tid < 80) nf4s[tid - 64] = NF4_TAB[tid - 64];
    __syncthreads();

    #pragma unroll
    for (int it = 0; it < 2; ++it) {
        const int i0 = (it * 256 + tid) * 8;
        float w[4][8];
        #pragma unroll
        for (int oo = 0; oo < 4; ++oo) {
            const size_t base = (size_t)(o0 + oo) * IN_DIM + i0;
            int4 c0 = *(const int4*)(codes + base);
            int4 c1 = *(const int4*)(codes + base + 4);
            const float sc = scales[(o0 + oo) * (IN_DIM / 64) + (i0 >> 6)];
            w[oo][0] = nf4s[c0.x] * sc; w[oo][1] = nf4s[c0.y] * sc;
            w[oo][2] = nf4s[c0.z] * sc; w[oo][3] = nf4s[c0.w] * sc;
            w[oo][4] = nf4s[c1.x] * sc; w[oo][5] = nf4s[c1.y] * sc;
            w[oo][6] = nf4s[c1.z] * sc; w[oo][7] = nf4s[c1.w] * sc;
        }
        #pragma unroll
        for (int r = 0; r < RANK; ++r) {
            float4 a0 = *(const float4*)(la + r * IN_DIM + i0);
            float4 a1 = *(const float4*)(la + r * IN_DIM + i0 + 4);
            #pragma unroll
            for (int oo = 0; oo < 4; ++oo) {
                const float b = lbs[oo][r];
                w[oo][0] += b * a0.x; w[oo][1] += b * a0.y;
                w[oo][2] += b * a0.z; w[oo][3] += b * a0.w;
                w[oo][4] += b * a1.x; w[oo][5] += b * a1.y;
                w[oo][6] += b * a1.z; w[oo][7] += b * a1.w;
            }
        }
        #pragma unroll
        for (int oo = 0; oo < 4; ++oo) {
            bf16x8 v;
            #pragma unroll
            for (int j = 0; j < 8; ++j) v[j] = (bf16_t)w[oo][j];
            *(bf16x8*)(W + (size_t)(o0 + oo) * IN_DIM + i0) = v;
        }
    }
}

// ---------------------------------------------------------------- cast x
__global__ __launch_bounds__(256) void cast_x(
    const float* __restrict__ x, bf16_t* __restrict__ y, int n8)
{
    const int stride = gridDim.x * blockDim.x;
    for (int i = blockIdx.x * blockDim.x + threadIdx.x; i < n8; i += stride) {
        const size_t e = (size_t)i * 8;
        float4 a = *(const float4*)(x + e);
        float4 b = *(const float4*)(x + e + 4);
        bf16x8 v;
        v[0] = (bf16_t)a.x; v[1] = (bf16_t)a.y; v[2] = (bf16_t)a.z; v[3] = (bf16_t)a.w;
        v[4] = (bf16_t)b.x; v[5] = (bf16_t)b.y; v[6] = (bf16_t)b.z; v[7] = (bf16_t)b.w;
        *(bf16x8*)(y + e) = v;
    }
}

// ---------------------------------------------------------------- GEMM
__global__ __launch_bounds__(512, 2) void gemm_bt(
    const bf16_t* __restrict__ A, const bf16_t* __restrict__ B,
    float* __restrict__ C)
{
    // [slot][A=0/B=1][khalf] 16KB regions; 2*2*2*16KB = 128 KB
    __shared__ __align__(128) char lds[131072];

    const int tid  = threadIdx.x;
    const int wave = tid >> 6;
    const int lane = tid & 63;

    const int flat = blockIdx.y * gridDim.x + blockIdx.x;     // 0..511
    const int swz  = (flat & 7) * 64 + (flat >> 3);           // XCD swizzle
    const int bx = swz & 15;
    const int by = swz >> 4;
    const int m0 = by * 256;
    const int n0 = bx * 256;

    const int wr = wave >> 2;         // 0..1
    const int wc = wave & 3;          // 0..3

    f32x4 acc[8][4];
    #pragma unroll
    for (int i = 0; i < 8; ++i)
        #pragma unroll
        for (int j = 0; j < 4; ++j) acc[i][j] = (f32x4)0.0f;

    const int frow = lane & 15;
    const int fch  = lane >> 4;

    // fragment byte offsets within a 16KB region (64B rows, R1 swizzle)
    int offA[8], offB0[2], offB1[2];
    #pragma unroll
    for (int f = 0; f < 8; ++f) {
        const int r = wr * 128 + f * 16 + frow;
        offA[f] = r * 64 + ((fch ^ ((r >> 1) & 3)) << 4);
    }
    #pragma unroll
    for (int n = 0; n < 2; ++n) {
        const int c0 = wc * 64 + n * 16 + frow;
        offB0[n] = c0 * 64 + ((fch ^ ((c0 >> 1) & 3)) << 4);
        const int c1 = wc * 64 + 32 + n * 16 + frow;
        offB1[n] = c1 * 64 + ((fch ^ ((c1 >> 1) & 3)) << 4);
    }

    // staging precompute: 2 x 16B loads per thread per half-region (16KB)
    const int d0 = tid * 16, d1 = 8192 + tid * 16;
    const int sr0 = d0 >> 6, sr1 = d1 >> 6;
    const int sg0 = ((d0 >> 4) & 3) ^ ((sr0 >> 1) & 3);
    const int sg1 = ((d1 >> 4) & 3) ^ ((sr1 >> 1) & 3);
    const char* gA = (const char*)A;
    const char* gB = (const char*)B;

    bf16x8 fA[8], fB0[2], fB1[2];

#define DS_A(SL, KH) do {                                                      \
    const char* bA_ = lds + (SL) * 65536 + (KH) * 16384;                       \
    _Pragma("unroll")                                                          \
    for (int f_ = 0; f_ < 8; ++f_) fA[f_] = *(const bf16x8*)(bA_ + offA[f_]);  \
} while (0)

#define DS_B(SL, KH, FB, OFB) do {                                             \
    const char* bB_ = lds + (SL) * 65536 + 32768 + (KH) * 16384;               \
    FB[0] = *(const bf16x8*)(bB_ + OFB[0]);                                    \
    FB[1] = *(const bf16x8*)(bB_ + OFB[1]);                                    \
} while (0)

#define STG(OPI, KH_, SL, T) do {                                              \
    const char* g_  = (OPI) ? gB : gA;                                         \
    const int   r0_ = (OPI) ? n0 : m0;                                         \
    const size_t ko_ = (size_t)(T) * 128 + (KH_) * 64;                         \
    const char* s0_ = g_ + (size_t)(r0_ + sr0) * 8192 + ko_ + (sg0 << 4);      \
    const char* s1_ = g_ + (size_t)(r0_ + sr1) * 8192 + ko_ + (sg1 << 4);      \
    char* db_ = lds + (SL) * 65536 + (OPI) * 32768 + (KH_) * 16384 + wave * 1024; \
    __builtin_amdgcn_global_load_lds(                                          \
        (const __attribute__((address_space(1))) void*)s0_,                    \
        (__attribute__((address_space(3))) void*)db_, 16, 0, 0);               \
    __builtin_amdgcn_global_load_lds(                                          \
        (const __attribute__((address_space(1))) void*)s1_,                    \
        (__attribute__((address_space(3))) void*)(db_ + 8192), 16, 0, 0);      \
} while (0)

#define MM(NH, FB) do {                                                        \
    __builtin_amdgcn_s_setprio(1);                                             \
    _Pragma("unroll")                                                          \
    for (int f_ = 0; f_ < 8; ++f_) {                                           \
        acc[f_][(NH)*2+0] = __builtin_amdgcn_mfma_f32_16x16x32_bf16(           \
            fA[f_], FB[0], acc[f_][(NH)*2+0], 0, 0, 0);                        \
        acc[f_][(NH)*2+1] = __builtin_amdgcn_mfma_f32_16x16x32_bf16(           \
            fA[f_], FB[1], acc[f_][(NH)*2+1], 0, 0, 0);                        \
    }                                                                          \
    __builtin_amdgcn_s_setprio(0);                                             \
} while (0)

#define BAR __builtin_amdgcn_s_barrier()
#define LG0 do { asm volatile("s_waitcnt lgkmcnt(0)" ::: "memory");            \
                 __builtin_amdgcn_sched_barrier(0); } while (0)
#define VM4 asm volatile("s_waitcnt vmcnt(4)" ::: "memory")
#define VM0 asm volatile("s_waitcnt vmcnt(0)" ::: "memory")

    // ---- prologue: tile0 all 4 half-regions (slot0), tile1 k0 halves (slot1)
    STG(0, 0, 0, 0); STG(1, 0, 0, 0); STG(0, 1, 0, 0); STG(1, 1, 0, 0);
    STG(0, 0, 1, 1); STG(1, 0, 1, 1);
    VM4;                                  // tile0 fully landed
    BAR;

    // ---- main loop: iter i computes K-tiles 2i (slot0), 2i+1 (slot1)
    for (int i = 0; i < 31; ++i) {
        const int tY  = 2 * i + 1;
        const int tX2 = 2 * i + 2;
        const int tY2 = 2 * i + 3;
        // p1 (k0,n0 of X)
        DS_A(0, 0); DS_B(0, 0, fB0, offB0); STG(0, 1, 1, tY);
        BAR; LG0; MM(0, fB0); BAR;
        // p2 (k0,n1)
        DS_B(0, 0, fB1, offB1); STG(1, 1, 1, tY);
        BAR; LG0; MM(1, fB1); BAR;
        // p3 (k1,n0)
        DS_A(0, 1); DS_B(0, 1, fB0, offB0); STG(0, 0, 0, tX2);
        BAR; LG0; MM(0, fB0); BAR;
        // p4 (k1,n1) + vmcnt checkpoint
        DS_B(0, 1, fB1, offB1); STG(1, 0, 0, tX2);
        VM4; BAR; LG0; MM(1, fB1); BAR;
        // p5 (k0,n0 of Y)
        DS_A(1, 0); DS_B(1, 0, fB0, offB0); STG(0, 1, 0, tX2);
        BAR; LG0; MM(0, fB0); BAR;
        // p6 (k0,n1)
        DS_B(1, 0, fB1, offB1); STG(1, 1, 0, tX2);
        BAR; LG0; MM(1, fB1); BAR;
        // p7 (k1,n0)
        DS_A(1, 1); DS_B(1, 1, fB0, offB0); STG(0, 0, 1, tY2);
        BAR; LG0; MM(0, fB0); BAR;
        // p8 (k1,n1) + vmcnt checkpoint
        DS_B(1, 1, fB1, offB1); STG(1, 0, 1, tY2);
        VM4; BAR; LG0; MM(1, fB1); BAR;
    }

    // ---- epilogue: K-tiles 62 (slot0), 63 (slot1); stage only 63's k1 halves
    DS_A(0, 0); DS_B(0, 0, fB0, offB0); STG(0, 1, 1, 63);
    BAR; LG0; MM(0, fB0); BAR;
    DS_B(0, 0, fB1, offB1); STG(1, 1, 1, 63);
    BAR; LG0; MM(1, fB1); BAR;
    DS_A(0, 1); DS_B(0, 1, fB0, offB0);
    BAR; LG0; MM(0, fB0); BAR;
    DS_B(0, 1, fB1, offB1);
    VM0; BAR; LG0; MM(1, fB1); BAR;
    DS_A(1, 0); DS_B(1, 0, fB0, offB0);
    BAR; LG0; MM(0, fB0); BAR;
    DS_B(1, 0, fB1, offB1);
    BAR; LG0; MM(1, fB1); BAR;
    DS_A(1, 1); DS_B(1, 1, fB0, offB0);
    BAR; LG0; MM(0, fB0); BAR;
    DS_B(1, 1, fB1, offB1);
    LG0; MM(1, fB1);

    // ---- C write: D layout col=lane&15, row=(lane>>4)*4+reg [m89-verified]
    const int crow = (lane >> 4) * 4;
    const int ccol = lane & 15;
    #pragma unroll
    for (int i = 0; i < 8; ++i) {
        #pragma unroll
        for (int j = 0; j < 4; ++j) {
            const int mb = m0 + wr * 128 + i * 16 + crow;
            const int nb = n0 + wc * 64 + j * 16 + ccol;
            #pragma unroll
            for (int r = 0; r < 4; ++r)
                C[(size_t)(mb + r) * OUT_DIM + nb] = acc[i][j][r];
        }
    }
#undef DS_A
#undef DS_B
#undef STG
#undef MM
#undef BAR
#undef LG0
#undef VM4
#undef VM0
}

// ---------------------------------------------------------------- launch
extern "C" void kernel_launch(void* const* d_in, const int* in_sizes, int n_in,
                              void* d_out, int out_size, void* d_ws, size_t ws_size,
                              hipStream_t stream) {
    const float* x      = (const float*)d_in[0];
    const int*   codes  = (const int*)d_in[1];
    const float* scales = (const float*)d_in[2];
    const float* la     = (const float*)d_in[3];
    const float* lb     = (const float*)d_in[4];
    float* out = (float*)d_out;

    bf16_t* W  = (bf16_t*)d_ws;
    bf16_t* xb = (bf16_t*)((char*)d_ws + (size_t)OUT_DIM * IN_DIM * 2);

    prep_w<<<OUT_DIM / 4, 256, 0, stream>>>(codes, scales, la, lb, W);
    cast_x<<<2048, 256, 0, stream>>>(x, xb, (M_TOK * IN_DIM) / 8);

    dim3 grid(OUT_DIM / 256, M_TOK / 256);   // (16, 32) = 512 blocks
    gemm_bt<<<grid, 512, 0, stream>>>(xb, W, out);
}